// Round 1
// baseline (367.071 us; speedup 1.0000x reference)
//
#include <hip/hip_runtime.h>

#define C_CH  128
#define NP    32768
#define K_PWL 20
#define LAT   8
#define HID   8
#define SLOTS 32

__device__ __forceinline__ float fast_tanh(float x) {
    float e = __expf(2.0f * x);          // v_exp_f32-based fast path
    return 1.0f - 2.0f / (e + 1.0f);     // == (e-1)/(e+1), saturates correctly
}

// monotone float<->uint encoding for atomic min/max on floats
__device__ __forceinline__ unsigned fenc(float f) {
    unsigned u = __float_as_uint(f);
    return (u & 0x80000000u) ? ~u : (u | 0x80000000u);
}
__device__ __forceinline__ float fdec(unsigned e) {
    unsigned u = (e & 0x80000000u) ? (e ^ 0x80000000u) : ~e;
    return __uint_as_float(u);
}

__global__ void init_stats(unsigned* cminE, unsigned* cmaxE, double* sums) {
    int t = threadIdx.x;
    if (t < C_CH) { cminE[t] = 0xFFFFFFFFu; cmaxE[t] = 0u; }
    if (t < 2 * SLOTS) sums[t] = 0.0;
}

// one thread per channel: pts MLP -> sort -> direction flip -> yp
__global__ void gen_yp(const float* __restrict__ zf,
                       const float* __restrict__ Wf1, const float* __restrict__ bf1,
                       const float* __restrict__ Wf2, const float* __restrict__ bf2,
                       const unsigned char* __restrict__ dirs_raw,
                       float* __restrict__ ypw) {
    int c = threadIdx.x;
    __shared__ int is_i32;
    if (c == 0) {
        // detect bool storage: int32 (all words 0/1) vs uint8 bytes
        const int* di = (const int*)dirs_raw;
        int ok = 1;
        for (int i = 0; i < 32; i++) { int v = di[i]; if (v != 0 && v != 1) ok = 0; }
        is_i32 = ok;
    }
    __syncthreads();
    if (c >= C_CH) return;

    float z[LAT];
    #pragma unroll
    for (int l = 0; l < LAT; l++) z[l] = zf[c * LAT + l];
    float h[HID];
    #pragma unroll
    for (int j = 0; j < HID; j++) {
        float a = bf1[j];
        #pragma unroll
        for (int l = 0; l < LAT; l++) a = fmaf(z[l], Wf1[l * HID + j], a);
        h[j] = fast_tanh(a);
    }
    float p[K_PWL];
    #pragma unroll
    for (int k = 0; k < K_PWL; k++) {
        float a = bf2[k];
        #pragma unroll
        for (int j = 0; j < HID; j++) a = fmaf(h[j], Wf2[j * K_PWL + k], a);
        p[k] = fast_tanh(a);
    }
    // insertion sort ascending (20 elems)
    for (int i = 1; i < K_PWL; i++) {
        float key = p[i];
        int j = i - 1;
        while (j >= 0 && p[j] > key) { p[j + 1] = p[j]; j--; }
        p[j + 1] = key;
    }
    int dir = is_i32 ? (((const int*)dirs_raw)[c] != 0) : (dirs_raw[c] != 0);
    for (int k = 0; k < K_PWL; k++)
        ypw[c * K_PWL + k] = dir ? p[k] : p[K_PWL - 1 - k];
}

// grid: (NP/256, C). Each thread computes one point's x and e raw values.
__global__ __launch_bounds__(256)
void pass1(const float* __restrict__ zx, const float* __restrict__ ze,
           const float* __restrict__ Wx1, const float* __restrict__ bx1,
           const float* __restrict__ Wx2, const float* __restrict__ bx2,
           const float* __restrict__ We1, const float* __restrict__ be1,
           const float* __restrict__ We2, const float* __restrict__ be2,
           float* __restrict__ xraw, float* __restrict__ eraw,
           unsigned* __restrict__ cminE, unsigned* __restrict__ cmaxE,
           double* __restrict__ sums) {
    // weights in LDS: Wx1[64] bx1[8] Wx2[8] bx2[1] We1[64] be1[8] We2[8] be2[1]
    __shared__ float sw[162];
    int t = threadIdx.x;
    if (t < 64)       sw[t] = Wx1[t];
    else if (t < 72)  sw[t] = bx1[t - 64];
    else if (t < 80)  sw[t] = Wx2[t - 72];
    else if (t == 80) sw[80] = bx2[0];
    else if (t < 145) sw[t] = We1[t - 81];
    else if (t < 153) sw[t] = be1[t - 145];
    else if (t < 161) sw[t] = We2[t - 153];
    else if (t == 161) sw[161] = be2[0];
    __syncthreads();

    int c = blockIdx.y;
    int n = blockIdx.x * 256 + t;
    size_t base = ((size_t)c * NP + n) * LAT;

    const float4* zxp = (const float4*)(zx + base);
    float4 a0 = zxp[0], a1 = zxp[1];
    const float4* zep = (const float4*)(ze + base);
    float4 b0 = zep[0], b1 = zep[1];

    // x MLP
    float xacc = sw[80];
    #pragma unroll
    for (int j = 0; j < HID; j++) {
        float hh = sw[64 + j];
        hh = fmaf(a0.x, sw[0 * 8 + j], hh);
        hh = fmaf(a0.y, sw[1 * 8 + j], hh);
        hh = fmaf(a0.z, sw[2 * 8 + j], hh);
        hh = fmaf(a0.w, sw[3 * 8 + j], hh);
        hh = fmaf(a1.x, sw[4 * 8 + j], hh);
        hh = fmaf(a1.y, sw[5 * 8 + j], hh);
        hh = fmaf(a1.z, sw[6 * 8 + j], hh);
        hh = fmaf(a1.w, sw[7 * 8 + j], hh);
        xacc = fmaf(fast_tanh(hh), sw[72 + j], xacc);
    }
    float xv = fast_tanh(xacc);

    // e MLP
    float eacc = sw[161];
    #pragma unroll
    for (int j = 0; j < HID; j++) {
        float hh = sw[145 + j];
        hh = fmaf(b0.x, sw[81 + 0 * 8 + j], hh);
        hh = fmaf(b0.y, sw[81 + 1 * 8 + j], hh);
        hh = fmaf(b0.z, sw[81 + 2 * 8 + j], hh);
        hh = fmaf(b0.w, sw[81 + 3 * 8 + j], hh);
        hh = fmaf(b1.x, sw[81 + 4 * 8 + j], hh);
        hh = fmaf(b1.y, sw[81 + 5 * 8 + j], hh);
        hh = fmaf(b1.z, sw[81 + 6 * 8 + j], hh);
        hh = fmaf(b1.w, sw[81 + 7 * 8 + j], hh);
        eacc = fmaf(fast_tanh(hh), sw[153 + j], eacc);
    }
    float ev = fast_tanh(eacc);

    xraw[(size_t)c * NP + n] = xv;
    eraw[(size_t)c * NP + n] = ev;

    // block reduction: min/max(x), sum/sumsq(e)
    float mn = xv, mx = xv, s = ev, s2 = ev * ev;
    #pragma unroll
    for (int o = 32; o > 0; o >>= 1) {
        mn = fminf(mn, __shfl_down(mn, o));
        mx = fmaxf(mx, __shfl_down(mx, o));
        s += __shfl_down(s, o);
        s2 += __shfl_down(s2, o);
    }
    __shared__ float rmn[4], rmx[4], rs[4], rs2[4];
    int wave = t >> 6, lane = t & 63;
    if (lane == 0) { rmn[wave] = mn; rmx[wave] = mx; rs[wave] = s; rs2[wave] = s2; }
    __syncthreads();
    if (t == 0) {
        for (int w = 1; w < 4; w++) {
            mn = fminf(mn, rmn[w]); mx = fmaxf(mx, rmx[w]);
            s += rs[w]; s2 += rs2[w];
        }
        atomicMin(&cminE[c], fenc(mn));
        atomicMax(&cmaxE[c], fenc(mx));
        int slot = (blockIdx.x + blockIdx.y) & (SLOTS - 1);
        atomicAdd(&sums[2 * slot], (double)s);
        atomicAdd(&sums[2 * slot + 1], (double)s2);
    }
}

// grid: NP/32 blocks. Tile = all 128 channels x 32 points; LDS transpose for
// coalesced [N,C] output stores.
__global__ __launch_bounds__(256)
void pass2(const float* __restrict__ xraw, const float* __restrict__ eraw,
           const float* __restrict__ ypw,
           const unsigned* __restrict__ cminE, const unsigned* __restrict__ cmaxE,
           const double* __restrict__ sums,
           float* __restrict__ out) {
    __shared__ float ytile[C_CH * 33];
    __shared__ float syp[C_CH * K_PWL];
    __shared__ float smin[C_CH], sinv[C_CH];
    __shared__ float sstat[2];   // mean, 0.1/std

    int t = threadIdx.x;
    for (int i = t; i < C_CH * K_PWL; i += 256) syp[i] = ypw[i];
    if (t < C_CH) {
        float mn = fdec(cminE[t]);
        float mx = fdec(cmaxE[t]);
        smin[t] = mn;
        sinv[t] = 1.0f / (mx - mn);
    }
    if (t == 0) {
        double s = 0.0, s2 = 0.0;
        for (int i = 0; i < SLOTS; i++) { s += sums[2 * i]; s2 += sums[2 * i + 1]; }
        double M = (double)C_CH * NP;
        double mean = s / M;
        double var = (s2 - s * s / M) / (M - 1.0);
        sstat[0] = (float)mean;
        sstat[1] = (float)(0.1 / sqrt(var));
    }
    __syncthreads();

    const float INV_DENOM = 1.0f / (1.0f / 19.0f + 1e-7f);
    float mean = sstat[0], escale = sstat[1];
    int n0 = blockIdx.x * 32;

    #pragma unroll
    for (int i = 0; i < 16; i++) {
        int idx = i * 256 + t;
        int c = idx >> 5;
        int j = idx & 31;
        size_t g = (size_t)c * NP + (n0 + j);
        float x = xraw[g];
        float e = eraw[g];
        float xn = (x - smin[c]) * sinv[c];
        int seg = (int)floorf(xn * 19.0f);
        seg = max(0, min(18, seg));
        float y0 = syp[c * K_PWL + seg];
        float y1 = syp[c * K_PWL + seg + 1];
        float y = fmaf((xn - (float)seg * (1.0f / 19.0f)) * INV_DENOM, y1 - y0, y0);
        y = fmaf(e - mean, escale, y);
        ytile[c * 33 + j] = y;
    }
    __syncthreads();
    #pragma unroll
    for (int i = 0; i < 16; i++) {
        int idx = i * 256 + t;
        int j = idx >> 7;
        int c = idx & 127;
        out[(size_t)(n0 + j) * C_CH + c] = ytile[c * 33 + j];
    }
}

extern "C" void kernel_launch(void* const* d_in, const int* in_sizes, int n_in,
                              void* d_out, int out_size, void* d_ws, size_t ws_size,
                              hipStream_t stream) {
    const float* zf  = (const float*)d_in[0];
    const float* zx  = (const float*)d_in[1];
    const float* ze  = (const float*)d_in[2];
    const float* Wx1 = (const float*)d_in[3];
    const float* bx1 = (const float*)d_in[4];
    const float* Wx2 = (const float*)d_in[5];
    const float* bx2 = (const float*)d_in[6];
    const float* We1 = (const float*)d_in[7];
    const float* be1 = (const float*)d_in[8];
    const float* We2 = (const float*)d_in[9];
    const float* be2 = (const float*)d_in[10];
    const float* Wf1 = (const float*)d_in[11];
    const float* bf1 = (const float*)d_in[12];
    const float* Wf2 = (const float*)d_in[13];
    const float* bf2 = (const float*)d_in[14];
    const unsigned char* dirs = (const unsigned char*)d_in[15];

    float* xraw = (float*)d_ws;
    float* eraw = xraw + (size_t)C_CH * NP;
    float* ypw  = eraw + (size_t)C_CH * NP;
    unsigned* cminE = (unsigned*)(ypw + C_CH * K_PWL);
    unsigned* cmaxE = cminE + C_CH;
    double* sums = (double*)(cmaxE + C_CH);   // byte offset is 8-aligned

    hipLaunchKernelGGL(init_stats, dim3(1), dim3(256), 0, stream,
                       cminE, cmaxE, sums);
    hipLaunchKernelGGL(gen_yp, dim3(1), dim3(128), 0, stream,
                       zf, Wf1, bf1, Wf2, bf2, dirs, ypw);
    hipLaunchKernelGGL(pass1, dim3(NP / 256, C_CH), dim3(256), 0, stream,
                       zx, ze, Wx1, bx1, Wx2, bx2, We1, be1, We2, be2,
                       xraw, eraw, cminE, cmaxE, sums);
    hipLaunchKernelGGL(pass2, dim3(NP / 32), dim3(256), 0, stream,
                       xraw, eraw, ypw, cminE, cmaxE, sums, (float*)d_out);
}

// Round 2
// 344.173 us; speedup vs baseline: 1.0665x; 1.0665x over previous
//
#include <hip/hip_runtime.h>

#define C_CH  128
#define NP    32768
#define K_PWL 20
#define LAT   8
#define HID   8
#define SLOTS 32
#define PTS   4          // points per thread in pass1

__device__ __forceinline__ float fast_tanh(float x) {
    float e = __expf(2.0f * x);                         // v_mul + v_exp_f32
    return fmaf(-2.0f, __builtin_amdgcn_rcpf(e + 1.0f), 1.0f);  // approx rcp: no IEEE div sequence
}

// monotone float<->uint encoding for atomic min/max on floats
__device__ __forceinline__ unsigned fenc(float f) {
    unsigned u = __float_as_uint(f);
    return (u & 0x80000000u) ? ~u : (u | 0x80000000u);
}
__device__ __forceinline__ float fdec(unsigned e) {
    unsigned u = (e & 0x80000000u) ? (e ^ 0x80000000u) : ~e;
    return __uint_as_float(u);
}

// one launch: init stats + per-channel yp generation (128 channels, 1 block)
__global__ void prep(const float* __restrict__ zf,
                     const float* __restrict__ Wf1, const float* __restrict__ bf1,
                     const float* __restrict__ Wf2, const float* __restrict__ bf2,
                     const unsigned char* __restrict__ dirs_raw,
                     float* __restrict__ ypw,
                     unsigned* cminE, unsigned* cmaxE, double* sums) {
    int t = threadIdx.x;
    if (t < C_CH) { cminE[t] = 0xFFFFFFFFu; cmaxE[t] = 0u; }
    if (t < 2 * SLOTS) sums[t] = 0.0;

    __shared__ int is_i32;
    if (t == 0) {
        // detect bool storage: int32 words (all 0/1) vs uint8 bytes
        const int* di = (const int*)dirs_raw;
        int ok = 1;
        for (int i = 0; i < 32; i++) { int v = di[i]; if (v != 0 && v != 1) ok = 0; }
        is_i32 = ok;
    }
    __syncthreads();
    if (t >= C_CH) return;
    int c = t;

    float z[LAT];
    #pragma unroll
    for (int l = 0; l < LAT; l++) z[l] = zf[c * LAT + l];
    float h[HID];
    #pragma unroll
    for (int j = 0; j < HID; j++) {
        float a = bf1[j];
        #pragma unroll
        for (int l = 0; l < LAT; l++) a = fmaf(z[l], Wf1[l * HID + j], a);
        h[j] = fast_tanh(a);
    }
    float p[K_PWL];
    #pragma unroll
    for (int k = 0; k < K_PWL; k++) {
        float a = bf2[k];
        #pragma unroll
        for (int j = 0; j < HID; j++) a = fmaf(h[j], Wf2[j * K_PWL + k], a);
        p[k] = fast_tanh(a);
    }
    // insertion sort ascending (20 elems)
    for (int i = 1; i < K_PWL; i++) {
        float key = p[i];
        int j = i - 1;
        while (j >= 0 && p[j] > key) { p[j + 1] = p[j]; j--; }
        p[j + 1] = key;
    }
    int dir = is_i32 ? (((const int*)dirs_raw)[c] != 0) : (dirs_raw[c] != 0);
    for (int k = 0; k < K_PWL; k++)
        ypw[c * K_PWL + k] = dir ? p[k] : p[K_PWL - 1 - k];
}

// grid: (NP/(256*PTS), C). Each thread computes PTS points (strided by 256
// for coalescing) -> 2*PTS independent tanh chains for ILP.
__global__ __launch_bounds__(256)
void pass1(const float* __restrict__ zx, const float* __restrict__ ze,
           const float* __restrict__ Wx1, const float* __restrict__ bx1,
           const float* __restrict__ Wx2, const float* __restrict__ bx2,
           const float* __restrict__ We1, const float* __restrict__ be1,
           const float* __restrict__ We2, const float* __restrict__ be2,
           float* __restrict__ xraw, float* __restrict__ eraw,
           unsigned* __restrict__ cminE, unsigned* __restrict__ cmaxE,
           double* __restrict__ sums) {
    // weights in LDS: Wx1[64] bx1[8] Wx2[8] bx2[1] We1[64] be1[8] We2[8] be2[1]
    __shared__ float sw[162];
    int t = threadIdx.x;
    if (t < 64)       sw[t] = Wx1[t];
    else if (t < 72)  sw[t] = bx1[t - 64];
    else if (t < 80)  sw[t] = Wx2[t - 72];
    else if (t == 80) sw[80] = bx2[0];
    else if (t < 145) sw[t] = We1[t - 81];
    else if (t < 153) sw[t] = be1[t - 145];
    else if (t < 161) sw[t] = We2[t - 153];
    else if (t == 161) sw[161] = be2[0];
    __syncthreads();

    int c = blockIdx.y;
    int n0 = blockIdx.x * (256 * PTS) + t;
    size_t row = (size_t)c * NP;
    const float4* zx4 = (const float4*)(zx + row * LAT);
    const float4* ze4 = (const float4*)(ze + row * LAT);

    float4 ax[PTS][2], ae[PTS][2];
    #pragma unroll
    for (int k = 0; k < PTS; k++) {
        int n = n0 + k * 256;
        ax[k][0] = zx4[2 * n];  ax[k][1] = zx4[2 * n + 1];
        ae[k][0] = ze4[2 * n];  ae[k][1] = ze4[2 * n + 1];
    }

    float xv[PTS], ev[PTS];
    #pragma unroll
    for (int k = 0; k < PTS; k++) {
        float acc = sw[80];
        #pragma unroll
        for (int j = 0; j < HID; j++) {
            float hh = sw[64 + j];
            hh = fmaf(ax[k][0].x, sw[0 * 8 + j], hh);
            hh = fmaf(ax[k][0].y, sw[1 * 8 + j], hh);
            hh = fmaf(ax[k][0].z, sw[2 * 8 + j], hh);
            hh = fmaf(ax[k][0].w, sw[3 * 8 + j], hh);
            hh = fmaf(ax[k][1].x, sw[4 * 8 + j], hh);
            hh = fmaf(ax[k][1].y, sw[5 * 8 + j], hh);
            hh = fmaf(ax[k][1].z, sw[6 * 8 + j], hh);
            hh = fmaf(ax[k][1].w, sw[7 * 8 + j], hh);
            acc = fmaf(fast_tanh(hh), sw[72 + j], acc);
        }
        xv[k] = fast_tanh(acc);
    }
    #pragma unroll
    for (int k = 0; k < PTS; k++) {
        float acc = sw[161];
        #pragma unroll
        for (int j = 0; j < HID; j++) {
            float hh = sw[145 + j];
            hh = fmaf(ae[k][0].x, sw[81 + 0 * 8 + j], hh);
            hh = fmaf(ae[k][0].y, sw[81 + 1 * 8 + j], hh);
            hh = fmaf(ae[k][0].z, sw[81 + 2 * 8 + j], hh);
            hh = fmaf(ae[k][0].w, sw[81 + 3 * 8 + j], hh);
            hh = fmaf(ae[k][1].x, sw[81 + 4 * 8 + j], hh);
            hh = fmaf(ae[k][1].y, sw[81 + 5 * 8 + j], hh);
            hh = fmaf(ae[k][1].z, sw[81 + 6 * 8 + j], hh);
            hh = fmaf(ae[k][1].w, sw[81 + 7 * 8 + j], hh);
            acc = fmaf(fast_tanh(hh), sw[153 + j], acc);
        }
        ev[k] = fast_tanh(acc);
    }

    float mn = xv[0], mx = xv[0], s = 0.f, s2 = 0.f;
    #pragma unroll
    for (int k = 0; k < PTS; k++) {
        xraw[row + n0 + k * 256] = xv[k];
        eraw[row + n0 + k * 256] = ev[k];
        mn = fminf(mn, xv[k]); mx = fmaxf(mx, xv[k]);
        s += ev[k]; s2 += ev[k] * ev[k];
    }

    #pragma unroll
    for (int o = 32; o > 0; o >>= 1) {
        mn = fminf(mn, __shfl_down(mn, o));
        mx = fmaxf(mx, __shfl_down(mx, o));
        s += __shfl_down(s, o);
        s2 += __shfl_down(s2, o);
    }
    __shared__ float rmn[4], rmx[4], rs[4], rs2[4];
    int wave = t >> 6, lane = t & 63;
    if (lane == 0) { rmn[wave] = mn; rmx[wave] = mx; rs[wave] = s; rs2[wave] = s2; }
    __syncthreads();
    if (t == 0) {
        for (int w = 1; w < 4; w++) {
            mn = fminf(mn, rmn[w]); mx = fmaxf(mx, rmx[w]);
            s += rs[w]; s2 += rs2[w];
        }
        atomicMin(&cminE[c], fenc(mn));
        atomicMax(&cmaxE[c], fenc(mx));
        int slot = (blockIdx.x + blockIdx.y) & (SLOTS - 1);
        atomicAdd(&sums[2 * slot], (double)s);
        atomicAdd(&sums[2 * slot + 1], (double)s2);
    }
}

// grid: NP/32 blocks. Tile = all 128 channels x 32 points; LDS transpose for
// coalesced [N,C] output stores.
__global__ __launch_bounds__(256)
void pass2(const float* __restrict__ xraw, const float* __restrict__ eraw,
           const float* __restrict__ ypw,
           const unsigned* __restrict__ cminE, const unsigned* __restrict__ cmaxE,
           const double* __restrict__ sums,
           float* __restrict__ out) {
    __shared__ float ytile[C_CH * 33];
    __shared__ float syp[C_CH * K_PWL];
    __shared__ float smin[C_CH], sinv[C_CH];
    __shared__ float sstat[2];   // mean, 0.1/std

    int t = threadIdx.x;
    for (int i = t; i < C_CH * K_PWL; i += 256) syp[i] = ypw[i];
    if (t < C_CH) {
        float mn = fdec(cminE[t]);
        float mx = fdec(cmaxE[t]);
        smin[t] = mn;
        sinv[t] = __builtin_amdgcn_rcpf(mx - mn);
    }
    if (t == 0) {
        double s = 0.0, s2 = 0.0;
        for (int i = 0; i < SLOTS; i++) { s += sums[2 * i]; s2 += sums[2 * i + 1]; }
        double M = (double)C_CH * NP;
        double mean = s / M;
        double var = (s2 - s * s / M) / (M - 1.0);
        sstat[0] = (float)mean;
        sstat[1] = (float)(0.1 / sqrt(var));
    }
    __syncthreads();

    const float INV_DENOM = 1.0f / (1.0f / 19.0f + 1e-7f);
    float mean = sstat[0], escale = sstat[1];
    int n0 = blockIdx.x * 32;

    #pragma unroll
    for (int i = 0; i < 16; i++) {
        int idx = i * 256 + t;
        int c = idx >> 5;
        int j = idx & 31;
        size_t g = (size_t)c * NP + (n0 + j);
        float x = xraw[g];
        float e = eraw[g];
        float xn = (x - smin[c]) * sinv[c];
        int seg = (int)floorf(xn * 19.0f);
        seg = max(0, min(18, seg));
        float y0 = syp[c * K_PWL + seg];
        float y1 = syp[c * K_PWL + seg + 1];
        float y = fmaf((xn - (float)seg * (1.0f / 19.0f)) * INV_DENOM, y1 - y0, y0);
        y = fmaf(e - mean, escale, y);
        ytile[c * 33 + j] = y;
    }
    __syncthreads();
    #pragma unroll
    for (int i = 0; i < 16; i++) {
        int idx = i * 256 + t;
        int j = idx >> 7;
        int c = idx & 127;
        out[(size_t)(n0 + j) * C_CH + c] = ytile[c * 33 + j];
    }
}

extern "C" void kernel_launch(void* const* d_in, const int* in_sizes, int n_in,
                              void* d_out, int out_size, void* d_ws, size_t ws_size,
                              hipStream_t stream) {
    const float* zf  = (const float*)d_in[0];
    const float* zx  = (const float*)d_in[1];
    const float* ze  = (const float*)d_in[2];
    const float* Wx1 = (const float*)d_in[3];
    const float* bx1 = (const float*)d_in[4];
    const float* Wx2 = (const float*)d_in[5];
    const float* bx2 = (const float*)d_in[6];
    const float* We1 = (const float*)d_in[7];
    const float* be1 = (const float*)d_in[8];
    const float* We2 = (const float*)d_in[9];
    const float* be2 = (const float*)d_in[10];
    const float* Wf1 = (const float*)d_in[11];
    const float* bf1 = (const float*)d_in[12];
    const float* Wf2 = (const float*)d_in[13];
    const float* bf2 = (const float*)d_in[14];
    const unsigned char* dirs = (const unsigned char*)d_in[15];

    float* xraw = (float*)d_ws;
    float* eraw = xraw + (size_t)C_CH * NP;
    float* ypw  = eraw + (size_t)C_CH * NP;
    unsigned* cminE = (unsigned*)(ypw + C_CH * K_PWL);
    unsigned* cmaxE = cminE + C_CH;
    double* sums = (double*)(cmaxE + C_CH);   // byte offset is 8-aligned

    hipLaunchKernelGGL(prep, dim3(1), dim3(256), 0, stream,
                       zf, Wf1, bf1, Wf2, bf2, dirs, ypw, cminE, cmaxE, sums);
    hipLaunchKernelGGL(pass1, dim3(NP / (256 * PTS), C_CH), dim3(256), 0, stream,
                       zx, ze, Wx1, bx1, Wx2, bx2, We1, be1, We2, be2,
                       xraw, eraw, cminE, cmaxE, sums);
    hipLaunchKernelGGL(pass2, dim3(NP / 32), dim3(256), 0, stream,
                       xraw, eraw, ypw, cminE, cmaxE, sums, (float*)d_out);
}